// Round 8
// baseline (349.489 us; speedup 1.0000x reference)
//
#include <hip/hip_runtime.h>

#define HH 512
#define WW 512
#define NB 4

// ---------------- Stage 1: 11x11 convs (1->8, pos & neg) + spike/WTA logic ----------------
// (unchanged from round 7 — verified absmax=0)
#define K1 11
#define PAD1 5
#define T1 32
#define IN1 42        // 32 + 10 halo
#define S1 44         // LDS row stride (floats)

__global__ __launch_bounds__(256, 4) void stage1_kernel(
    const float* __restrict__ inp, const float* __restrict__ Wb,
    unsigned char* __restrict__ border)
{
    __shared__ __align__(16) float s0[IN1 * S1];
    __shared__ __align__(16) float s1[IN1 * S1];

    const int b   = blockIdx.z;
    const int tx0 = blockIdx.x * T1;
    const int ty0 = blockIdx.y * T1;
    const float* in0 = inp + ((size_t)b * 2 + 0) * (HH * WW);
    const float* in1 = inp + ((size_t)b * 2 + 1) * (HH * WW);

    for (int i = threadIdx.x; i < IN1 * IN1; i += 256) {
        int iy = i / IN1, ix = i - iy * IN1;
        int gy = ty0 + iy - PAD1, gx = tx0 + ix - PAD1;
        bool ok = (gy >= 0) & (gy < HH) & (gx >= 0) & (gx < WW);
        int idx = gy * WW + gx;
        s0[iy * S1 + ix] = ok ? in0[idx] : 0.f;
        s1[iy * S1 + ix] = ok ? in1[idx] : 0.f;
    }
    __syncthreads();

    const int lx = threadIdx.x & 7;   // 8 groups of 4 px -> 32 wide
    const int ly = threadIdx.x >> 3;  // 32 rows
    const int px = lx * 4;
    const int py = ly;

    unsigned bitP = 0, bitN = 0;

    #pragma unroll
    for (int half = 0; half < 2; half++) {       // static cb => static weight indices
        const int cb = half * 4;
        float aP[4][4], aN[4][4];
        #pragma unroll
        for (int cc = 0; cc < 4; cc++)
            #pragma unroll
            for (int p = 0; p < 4; p++) { aP[cc][p] = 0.f; aN[cc][p] = 0.f; }

        #pragma unroll 1
        for (int ky = 0; ky < K1; ky++) {
            {   // plane P
                const float4* rp = (const float4*)&s0[(py + ky) * S1 + px];
                float a[16];
                #pragma unroll
                for (int r = 0; r < 4; r++) *(float4*)&a[4 * r] = rp[r];
                #pragma unroll
                for (int cc = 0; cc < 4; cc++) {
                    #pragma unroll
                    for (int kx = 0; kx < K1; kx++) {
                        const float wv = Wb[(cb + cc) * 121 + ky * 11 + kx]; // uniform s_load
                        #pragma unroll
                        for (int p = 0; p < 4; p++)
                            aP[cc][p] = fmaf(a[kx + p], wv, aP[cc][p]);
                    }
                }
            }
            {   // plane N (same weights, already in SGPRs)
                const float4* rp = (const float4*)&s1[(py + ky) * S1 + px];
                float a[16];
                #pragma unroll
                for (int r = 0; r < 4; r++) *(float4*)&a[4 * r] = rp[r];
                #pragma unroll
                for (int cc = 0; cc < 4; cc++) {
                    #pragma unroll
                    for (int kx = 0; kx < K1; kx++) {
                        const float wv = Wb[(cb + cc) * 121 + ky * 11 + kx];
                        #pragma unroll
                        for (int p = 0; p < 4; p++)
                            aN[cc][p] = fmaf(a[kx + p], wv, aN[cc][p]);
                    }
                }
            }
        }
        #pragma unroll
        for (int cc = 0; cc < 4; cc++)
            #pragma unroll
            for (int p = 0; p < 4; p++) {
                bitP |= (aP[cc][p] >= 1.f ? 1u : 0u) << (16 * half + cc * 4 + p);
                bitN |= (aN[cc][p] >= 1.f ? 1u : 0u) << (16 * half + cc * 4 + p);
            }
    }

    // ---- spike / WTA logic from bitmasks ----
    const int gy = ty0 + py;
    const int gxbase = tx0 + px;

    float vm[4];
    #pragma unroll
    for (int p = 0; p < 4; p++)
        vm[p] = s0[(py + PAD1) * S1 + px + PAD1 + p]
              + s1[(py + PAD1) * S1 + px + PAD1 + p];

    float b13[4][4], b24[4][4];       // [o][p]
    #pragma unroll
    for (int o = 0; o < 4; o++) {
        #pragma unroll
        for (int p = 0; p < 4; p++) {
            float pe = (float)((bitP >> (8 * o + p))     & 1u);
            float po = (float)((bitP >> (8 * o + 4 + p)) & 1u);
            float ne = (float)((bitN >> (8 * o + p))     & 1u);
            float no = (float)((bitN >> (8 * o + 4 + p)) & 1u);
            float sa = (vm[p] * (pe - 1.5f * no) >= 1.f) ? 1.f : 0.f;
            float sb = (vm[p] * (ne - 1.5f * po) >= 1.f) ? 1.f : 0.f;
            b13[o][p] = sa + sb;
            float sc = (vm[p] * (po - 1.5f * ne) >= 1.f) ? 1.f : 0.f;
            float sd = (vm[p] * (no - 1.5f * pe) >= 1.f) ? 1.f : 0.f;
            b24[o][p] = sc + sd;
        }
    }
    float mxp[4];
    #pragma unroll
    for (int p = 0; p < 4; p++) {
        float m = 0.f;
        #pragma unroll
        for (int o = 0; o < 4; o++) m = fmaxf(m, fabsf(b13[o][p] - b24[o][p]));
        mxp[p] = m;
    }
    #pragma unroll
    for (int o = 0; o < 4; o++) {
        unsigned w0 = 0, w1 = 0, w2 = 0, w3 = 0;
        #pragma unroll
        for (int p = 0; p < 4; p++) {
            float d   = b13[o][p] - b24[o][p];
            float wta = (fabsf(d) == mxp[p]) ? 1.f : 0.f;
            float b1p = (wta * d >= 1.f)    ? 1.f : 0.f;
            float b1n = (-(wta * d) >= 1.f) ? 1.f : 0.f;
            w0 |= (unsigned)(unsigned char)(b1p * b13[o][p]) << (8 * p);
            w1 |= (unsigned)(unsigned char)(b1p * b24[o][p]) << (8 * p);  // G_INH = 1.0
            w2 |= (unsigned)(unsigned char)(b1n * b24[o][p]) << (8 * p);
            w3 |= (unsigned)(unsigned char)(b1n * b13[o][p]) << (8 * p);  // G_INH = 1.0
        }
        size_t base = (((size_t)b * 16 + 4 * o) * HH + gy) * WW + gxbase;
        *(unsigned*)&border[base]                       = w0;
        *(unsigned*)&border[base + (size_t)HH * WW]     = w1;
        *(unsigned*)&border[base + (size_t)2 * HH * WW] = w2;
        *(unsigned*)&border[base + (size_t)3 * HH * WW] = w3;
    }
}

// ---------------- Stage 2: depthwise 23x23 conv, u8 LDS tile, 4 rows/thread --------------
// Thread = 8 px (x) * 4 rows (y); tile 32x256. u8 tile in LDS; ky-blocks of 3 taps with
// the 69 block weights hoisted to SGPRs. Packed-u8 window => compiler remat (if any) is a
// 1-cycle v_cvt, never a ds_read.
#define K2 23
#define PAD2 11
#define T2X 32
#define T2Y 256
#define SROW 18        // LDS row stride in dwords (72 B)
#define R2T (T2Y + K2 - 1)   // 278 staged rows

__device__ __forceinline__ float ubyte_f(unsigned dw, int byi) {
    return (float)((dw >> (8 * byi)) & 0xffu);   // -> v_cvt_f32_ubyteN
}

__global__ __launch_bounds__(256, 4) void stage2_kernel(
    const unsigned char* __restrict__ border, const float* __restrict__ Wg,
    unsigned char* __restrict__ gsp)
{
    __shared__ unsigned tile[R2T * SROW];   // u8 tile, 19.5 KB

    const int z   = blockIdx.z;
    const int b   = z >> 4;
    const int c   = z & 15;
    const int tx0 = blockIdx.x * T2X;
    const int ty0 = blockIdx.y * T2Y;
    const unsigned char* bp = border + ((size_t)b * 16 + c) * (HH * WW);

    // ---- stage u8 rows [ty0-11, ty0+267), cols [tx0-12, tx0+52) as dwords ----
    for (int i = threadIdx.x; i < R2T * 16; i += 256) {
        int iy = i >> 4, cc = i & 15;
        int gy  = ty0 - PAD2 + iy;
        int gx0 = tx0 - 12 + 4 * cc;       // 4-aligned
        unsigned u = 0;
        if (((unsigned)gy < HH) & ((unsigned)gx0 < WW))
            u = *(const unsigned*)(bp + (size_t)gy * WW + gx0);
        tile[iy * SROW + cc] = u;
    }
    __syncthreads();

    const int lx = threadIdx.x & 3;    // 4 x-groups of 8 px -> 32 wide
    const int ly = threadIdx.x >> 2;   // 64 y-groups of 4 rows -> 256 tall
    const int px = lx * 8;
    const int py = ly * 4;

    float acc[4][8];
    #pragma unroll
    for (int dy = 0; dy < 4; dy++)
        #pragma unroll
        for (int p = 0; p < 8; p++) acc[dy][p] = 0.f;

    const float* wc = Wg + c * (K2 * K2);

    // 7 full ky-blocks of 3 taps, then a tail block of 2 (ky 21,22)
    #pragma unroll 1
    for (int kyb = 0; kyb < 7; kyb++) {
        const int b0 = kyb * 3;
        #pragma unroll
        for (int r = 0; r < 6; r++) {                  // input rows py+b0+r
            const int trow = py + b0 + r;
            unsigned d[8];
            const uint2* tp2 = (const uint2*)&tile[trow * SROW + 2 * lx];
            #pragma unroll
            for (int r2 = 0; r2 < 4; r2++) { uint2 v = tp2[r2]; d[2*r2] = v.x; d[2*r2+1] = v.y; }
            float a[31];
            #pragma unroll
            for (int j = 1; j <= 30; j++) a[j] = ubyte_f(d[j >> 2], j & 3);
            #pragma unroll
            for (int jk = 0; jk < 3; jk++) {
                const int dy = r - jk;
                if (dy >= 0 && dy < 4) {               // compile-time after unroll
                    #pragma unroll
                    for (int kx = 0; kx < 23; kx++) {
                        const float wv = wc[(b0 + jk) * 23 + kx];   // uniform -> s_load
                        #pragma unroll
                        for (int p = 0; p < 8; p++)
                            acc[dy][p] = fmaf(a[p + kx + 1], wv, acc[dy][p]);
                    }
                }
            }
        }
    }
    {   // tail: ky 21,22
        const int b0 = 21;
        #pragma unroll
        for (int r = 0; r < 5; r++) {
            const int trow = py + b0 + r;
            unsigned d[8];
            const uint2* tp2 = (const uint2*)&tile[trow * SROW + 2 * lx];
            #pragma unroll
            for (int r2 = 0; r2 < 4; r2++) { uint2 v = tp2[r2]; d[2*r2] = v.x; d[2*r2+1] = v.y; }
            float a[31];
            #pragma unroll
            for (int j = 1; j <= 30; j++) a[j] = ubyte_f(d[j >> 2], j & 3);
            #pragma unroll
            for (int jk = 0; jk < 2; jk++) {
                const int dy = r - jk;
                if (dy >= 0 && dy < 4) {
                    #pragma unroll
                    for (int kx = 0; kx < 23; kx++) {
                        const float wv = wc[(b0 + jk) * 23 + kx];
                        #pragma unroll
                        for (int p = 0; p < 8; p++)
                            acc[dy][p] = fmaf(a[p + kx + 1], wv, acc[dy][p]);
                    }
                }
            }
        }
    }

    // ---- spike + write u8 plane ----
    const int ox = tx0 + px;               // multiple of 8 -> uint2 store OK
    unsigned char* gp = gsp + ((size_t)b * 16 + c) * (HH * WW);
    #pragma unroll
    for (int dy = 0; dy < 4; dy++) {
        const int oy = ty0 + py + dy;
        unsigned lo = 0, hi = 0;
        #pragma unroll
        for (int p = 0; p < 4; p++) lo |= (acc[dy][p]     >= 1.f ? 1u : 0u) << (8 * p);
        #pragma unroll
        for (int p = 0; p < 4; p++) hi |= (acc[dy][p + 4] >= 1.f ? 1u : 0u) << (8 * p);
        uint2 v; v.x = lo; v.y = hi;
        *(uint2*)&gp[(size_t)oy * WW + ox] = v;
    }
}

// ---------------- Stage 3: combine 16 spike planes -> output ----------------
__global__ __launch_bounds__(256) void combine_kernel(
    const unsigned char* __restrict__ gsp, float* __restrict__ out)
{
    const int idx = blockIdx.x * 256 + threadIdx.x;   // uint granules
    const int b = idx >> 16;
    const int r = idx & 65535;
    const unsigned* g = (const unsigned*)gsp;
    const int pb = b * 16;
    unsigned s = 0;
    #pragma unroll
    for (int o = 0; o < 4; o++) {
        unsigned g0 = g[(size_t)(pb + 4 * o + 0) * 65536 + r];
        unsigned g1 = g[(size_t)(pb + 4 * o + 1) * 65536 + r];
        unsigned g2 = g[(size_t)(pb + 4 * o + 2) * 65536 + r];
        unsigned g3 = g[(size_t)(pb + 4 * o + 3) * 65536 + r];
        s += ((g0 & ~g1) & 0x01010101u) + ((g2 & ~g3) & 0x01010101u);
    }
    float4 f;
    f.x = (float)(s & 255u);
    f.y = (float)((s >> 8) & 255u);
    f.z = (float)((s >> 16) & 255u);
    f.w = (float)(s >> 24);
    ((float4*)out)[idx] = f;
}

extern "C" void kernel_launch(void* const* d_in, const int* in_sizes, int n_in,
                              void* d_out, int out_size, void* d_ws, size_t ws_size,
                              hipStream_t stream)
{
    const float* inp = (const float*)d_in[0];   // (4,2,512,512) f32
    const float* Wb  = (const float*)d_in[1];   // (8,1,11,11)   f32
    const float* Wg  = (const float*)d_in[2];   // (16,1,23,23)  f32
    unsigned char* border = (unsigned char*)d_ws;                       // 16.78 MB
    unsigned char* gsp    = border + (size_t)NB * 16 * HH * WW;         // +16.78 MB
    float* out = (float*)d_out;                 // (4,512,512)   f32

    dim3 blk(256);
    dim3 g1(WW / T1, HH / T1, NB);          // 16x16x4 = 1024 blocks
    stage1_kernel<<<g1, blk, 0, stream>>>(inp, Wb, border);
    dim3 g2(WW / T2X, HH / T2Y, NB * 16);   // 16x2x64 = 2048 blocks
    stage2_kernel<<<g2, blk, 0, stream>>>(border, Wg, gsp);
    dim3 g3((NB * HH * WW / 4) / 256);      // 1024 blocks
    combine_kernel<<<g3, blk, 0, stream>>>(gsp, out);
}

// Round 9
// 289.558 us; speedup vs baseline: 1.2070x; 1.2070x over previous
//
#include <hip/hip_runtime.h>

#define HH 512
#define WW 512
#define NB 4

// ---------------- Stage 1: 11x11 convs (1->8, pos & neg) + spike/WTA logic ----------------
// Two sequential plane passes (P then N); each pass: all 8 channels in one ky loop.
// Liveness per pass: acc[8][4]=32 + a[16] ~= 48 < the ~64-VGPR cap the backend enforces.
// DS traffic: 2 passes x 11 ky x 4 b128 = 88 b128/thread.
#define K1 11
#define PAD1 5
#define T1 32
#define IN1 42        // 32 + 10 halo
#define S1 44         // LDS row stride (floats)

__device__ __forceinline__ unsigned conv8_pass(const float* __restrict__ sm,
                                               const float* __restrict__ Wb,
                                               int py, int px)
{
    float acc[8][4];
    #pragma unroll
    for (int c = 0; c < 8; c++)
        #pragma unroll
        for (int p = 0; p < 4; p++) acc[c][p] = 0.f;

    #pragma unroll 1
    for (int ky = 0; ky < K1; ky++) {
        const float4* rp = (const float4*)&sm[(py + ky) * S1 + px];
        float a[16];
        #pragma unroll
        for (int r = 0; r < 4; r++) *(float4*)&a[4 * r] = rp[r];
        #pragma unroll
        for (int c = 0; c < 8; c++) {
            #pragma unroll
            for (int kx = 0; kx < K1; kx++) {
                const float wv = Wb[c * 121 + ky * 11 + kx];   // uniform -> s_load
                #pragma unroll
                for (int p = 0; p < 4; p++)
                    acc[c][p] = fmaf(a[kx + p], wv, acc[c][p]);
            }
        }
    }
    unsigned bits = 0;
    #pragma unroll
    for (int c = 0; c < 8; c++)
        #pragma unroll
        for (int p = 0; p < 4; p++)
            bits |= (acc[c][p] >= 1.f ? 1u : 0u) << (c * 4 + p);
    return bits;
}

__global__ __launch_bounds__(256, 4) void stage1_kernel(
    const float* __restrict__ inp, const float* __restrict__ Wb,
    unsigned char* __restrict__ border)
{
    __shared__ __align__(16) float s0[IN1 * S1];
    __shared__ __align__(16) float s1[IN1 * S1];

    const int b   = blockIdx.z;
    const int tx0 = blockIdx.x * T1;
    const int ty0 = blockIdx.y * T1;
    const float* in0 = inp + ((size_t)b * 2 + 0) * (HH * WW);
    const float* in1 = inp + ((size_t)b * 2 + 1) * (HH * WW);

    for (int i = threadIdx.x; i < IN1 * IN1; i += 256) {
        int iy = i / IN1, ix = i - iy * IN1;
        int gy = ty0 + iy - PAD1, gx = tx0 + ix - PAD1;
        bool ok = (gy >= 0) & (gy < HH) & (gx >= 0) & (gx < WW);
        int idx = gy * WW + gx;
        s0[iy * S1 + ix] = ok ? in0[idx] : 0.f;
        s1[iy * S1 + ix] = ok ? in1[idx] : 0.f;
    }
    __syncthreads();

    const int lx = threadIdx.x & 7;   // 8 groups of 4 px -> 32 wide
    const int ly = threadIdx.x >> 3;  // 32 rows
    const int px = lx * 4;
    const int py = ly;

    const unsigned bitP = conv8_pass(s0, Wb, py, px);
    const unsigned bitN = conv8_pass(s1, Wb, py, px);

    // ---- spike / WTA logic from bitmasks (verified layout: channel c at bit c*4+p) ----
    const int gy = ty0 + py;
    const int gxbase = tx0 + px;

    float vm[4];
    #pragma unroll
    for (int p = 0; p < 4; p++)
        vm[p] = s0[(py + PAD1) * S1 + px + PAD1 + p]
              + s1[(py + PAD1) * S1 + px + PAD1 + p];

    float b13[4][4], b24[4][4];       // [o][p]
    #pragma unroll
    for (int o = 0; o < 4; o++) {
        #pragma unroll
        for (int p = 0; p < 4; p++) {
            float pe = (float)((bitP >> (8 * o + p))     & 1u);
            float po = (float)((bitP >> (8 * o + 4 + p)) & 1u);
            float ne = (float)((bitN >> (8 * o + p))     & 1u);
            float no = (float)((bitN >> (8 * o + 4 + p)) & 1u);
            float sa = (vm[p] * (pe - 1.5f * no) >= 1.f) ? 1.f : 0.f;
            float sb = (vm[p] * (ne - 1.5f * po) >= 1.f) ? 1.f : 0.f;
            b13[o][p] = sa + sb;
            float sc = (vm[p] * (po - 1.5f * ne) >= 1.f) ? 1.f : 0.f;
            float sd = (vm[p] * (no - 1.5f * pe) >= 1.f) ? 1.f : 0.f;
            b24[o][p] = sc + sd;
        }
    }
    float mxp[4];
    #pragma unroll
    for (int p = 0; p < 4; p++) {
        float m = 0.f;
        #pragma unroll
        for (int o = 0; o < 4; o++) m = fmaxf(m, fabsf(b13[o][p] - b24[o][p]));
        mxp[p] = m;
    }
    #pragma unroll
    for (int o = 0; o < 4; o++) {
        unsigned w0 = 0, w1 = 0, w2 = 0, w3 = 0;
        #pragma unroll
        for (int p = 0; p < 4; p++) {
            float d   = b13[o][p] - b24[o][p];
            float wta = (fabsf(d) == mxp[p]) ? 1.f : 0.f;
            float b1p = (wta * d >= 1.f)    ? 1.f : 0.f;
            float b1n = (-(wta * d) >= 1.f) ? 1.f : 0.f;
            w0 |= (unsigned)(unsigned char)(b1p * b13[o][p]) << (8 * p);
            w1 |= (unsigned)(unsigned char)(b1p * b24[o][p]) << (8 * p);  // G_INH = 1.0
            w2 |= (unsigned)(unsigned char)(b1n * b24[o][p]) << (8 * p);
            w3 |= (unsigned)(unsigned char)(b1n * b13[o][p]) << (8 * p);  // G_INH = 1.0
        }
        size_t base = (((size_t)b * 16 + 4 * o) * HH + gy) * WW + gxbase;
        *(unsigned*)&border[base]                       = w0;
        *(unsigned*)&border[base + (size_t)HH * WW]     = w1;
        *(unsigned*)&border[base + (size_t)2 * HH * WW] = w2;
        *(unsigned*)&border[base + (size_t)3 * HH * WW] = w3;
    }
}

// ---------------- Stage 2: depthwise 23x23 conv, u8 LDS tile + ky-blocking ----------------
// EXACT round-7 version (186 us, VGPR=64, no spill). Thread = 8 px (x) * 2 rows (y);
// tile 32x128; u8 tile in LDS; ky-blocks of 3 taps, 69 block weights hoisted to SGPRs.
// Liveness acc[2][8]=16 + a[31] + d[8] ~= 58 -- fits the 64-VGPR cap (4 rows spilled!).
#define K2 23
#define PAD2 11
#define T2X 32
#define T2Y 128
#define SROW 18        // LDS row stride in dwords (72 B)
#define R2 150         // staged rows: ty0-11 .. ty0+138

__device__ __forceinline__ float ubyte_f(unsigned dw, int byi) {
    return (float)((dw >> (8 * byi)) & 0xffu);   // -> v_cvt_f32_ubyteN
}

__global__ __launch_bounds__(256, 4) void stage2_kernel(
    const unsigned char* __restrict__ border, const float* __restrict__ Wg,
    unsigned char* __restrict__ gsp)
{
    __shared__ unsigned tile[R2 * SROW];   // u8 tile, 10.8 KB

    const int z   = blockIdx.z;
    const int b   = z >> 4;
    const int c   = z & 15;
    const int tx0 = blockIdx.x * T2X;
    const int ty0 = blockIdx.y * T2Y;
    const unsigned char* bp = border + ((size_t)b * 16 + c) * (HH * WW);

    // ---- stage u8 rows [ty0-11, ty0+139), cols [tx0-12, tx0+52) as dwords ----
    for (int i = threadIdx.x; i < R2 * 16; i += 256) {
        int iy = i >> 4, cc = i & 15;
        int gy  = ty0 - PAD2 + iy;
        int gx0 = tx0 - 12 + 4 * cc;       // 4-aligned; in range iff 0<=gx0<=508
        unsigned u = 0;
        if (((unsigned)gy < HH) & ((unsigned)gx0 < WW))
            u = *(const unsigned*)(bp + (size_t)gy * WW + gx0);
        tile[iy * SROW + cc] = u;
    }
    __syncthreads();

    const int lx = threadIdx.x & 3;    // 4 x-groups of 8 px -> 32 wide
    const int ly = threadIdx.x >> 2;   // 64 y-groups of 2 rows -> 128 tall
    const int px = lx * 8;
    const int py = ly * 2;

    float acc[2][8];
    #pragma unroll
    for (int dy = 0; dy < 2; dy++)
        #pragma unroll
        for (int p = 0; p < 8; p++) acc[dy][p] = 0.f;

    const float* wc = Wg + c * (K2 * K2);

    // 7 full ky-blocks of 3 taps, then a tail block of 2 (ky 21,22)
    #pragma unroll 1
    for (int kyb = 0; kyb < 7; kyb++) {
        const int b0 = kyb * 3;
        #pragma unroll
        for (int r = 0; r < 4; r++) {                  // input rows py+b0+r
            const int trow = py + b0 + r;
            unsigned d[8];
            const uint2* tp2 = (const uint2*)&tile[trow * SROW + 2 * lx];
            #pragma unroll
            for (int r2 = 0; r2 < 4; r2++) { uint2 v = tp2[r2]; d[2*r2] = v.x; d[2*r2+1] = v.y; }
            float a[31];
            #pragma unroll
            for (int j = 1; j <= 30; j++) a[j] = ubyte_f(d[j >> 2], j & 3);
            #pragma unroll
            for (int jk = 0; jk < 3; jk++) {
                const int dy = r - jk;
                if (dy >= 0 && dy < 2) {               // compile-time after unroll
                    #pragma unroll
                    for (int kx = 0; kx < 23; kx++) {
                        const float wv = wc[(b0 + jk) * 23 + kx];   // uniform -> s_load
                        #pragma unroll
                        for (int p = 0; p < 8; p++)
                            acc[dy][p] = fmaf(a[p + kx + 1], wv, acc[dy][p]);
                    }
                }
            }
        }
    }
    {   // tail: ky 21,22
        const int b0 = 21;
        #pragma unroll
        for (int r = 0; r < 3; r++) {
            const int trow = py + b0 + r;
            unsigned d[8];
            const uint2* tp2 = (const uint2*)&tile[trow * SROW + 2 * lx];
            #pragma unroll
            for (int r2 = 0; r2 < 4; r2++) { uint2 v = tp2[r2]; d[2*r2] = v.x; d[2*r2+1] = v.y; }
            float a[31];
            #pragma unroll
            for (int j = 1; j <= 30; j++) a[j] = ubyte_f(d[j >> 2], j & 3);
            #pragma unroll
            for (int jk = 0; jk < 2; jk++) {
                const int dy = r - jk;
                if (dy >= 0 && dy < 2) {
                    #pragma unroll
                    for (int kx = 0; kx < 23; kx++) {
                        const float wv = wc[(b0 + jk) * 23 + kx];
                        #pragma unroll
                        for (int p = 0; p < 8; p++)
                            acc[dy][p] = fmaf(a[p + kx + 1], wv, acc[dy][p]);
                    }
                }
            }
        }
    }

    // ---- spike + write u8 plane ----
    const int ox = tx0 + px;               // multiple of 8 -> uint2 store OK
    unsigned char* gp = gsp + ((size_t)b * 16 + c) * (HH * WW);
    #pragma unroll
    for (int dy = 0; dy < 2; dy++) {
        const int oy = ty0 + py + dy;
        unsigned lo = 0, hi = 0;
        #pragma unroll
        for (int p = 0; p < 4; p++) lo |= (acc[dy][p]     >= 1.f ? 1u : 0u) << (8 * p);
        #pragma unroll
        for (int p = 0; p < 4; p++) hi |= (acc[dy][p + 4] >= 1.f ? 1u : 0u) << (8 * p);
        uint2 v; v.x = lo; v.y = hi;
        *(uint2*)&gp[(size_t)oy * WW + ox] = v;
    }
}

// ---------------- Stage 3: combine 16 spike planes -> output ----------------
__global__ __launch_bounds__(256) void combine_kernel(
    const unsigned char* __restrict__ gsp, float* __restrict__ out)
{
    const int idx = blockIdx.x * 256 + threadIdx.x;   // uint granules
    const int b = idx >> 16;
    const int r = idx & 65535;
    const unsigned* g = (const unsigned*)gsp;
    const int pb = b * 16;
    unsigned s = 0;
    #pragma unroll
    for (int o = 0; o < 4; o++) {
        unsigned g0 = g[(size_t)(pb + 4 * o + 0) * 65536 + r];
        unsigned g1 = g[(size_t)(pb + 4 * o + 1) * 65536 + r];
        unsigned g2 = g[(size_t)(pb + 4 * o + 2) * 65536 + r];
        unsigned g3 = g[(size_t)(pb + 4 * o + 3) * 65536 + r];
        s += ((g0 & ~g1) & 0x01010101u) + ((g2 & ~g3) & 0x01010101u);
    }
    float4 f;
    f.x = (float)(s & 255u);
    f.y = (float)((s >> 8) & 255u);
    f.z = (float)((s >> 16) & 255u);
    f.w = (float)(s >> 24);
    ((float4*)out)[idx] = f;
}

extern "C" void kernel_launch(void* const* d_in, const int* in_sizes, int n_in,
                              void* d_out, int out_size, void* d_ws, size_t ws_size,
                              hipStream_t stream)
{
    const float* inp = (const float*)d_in[0];   // (4,2,512,512) f32
    const float* Wb  = (const float*)d_in[1];   // (8,1,11,11)   f32
    const float* Wg  = (const float*)d_in[2];   // (16,1,23,23)  f32
    unsigned char* border = (unsigned char*)d_ws;                       // 16.78 MB
    unsigned char* gsp    = border + (size_t)NB * 16 * HH * WW;         // +16.78 MB
    float* out = (float*)d_out;                 // (4,512,512)   f32

    dim3 blk(256);
    dim3 g1(WW / T1, HH / T1, NB);          // 16x16x4 = 1024 blocks
    stage1_kernel<<<g1, blk, 0, stream>>>(inp, Wb, border);
    dim3 g2(WW / T2X, HH / T2Y, NB * 16);   // 16x4x64 = 4096 blocks
    stage2_kernel<<<g2, blk, 0, stream>>>(border, Wg, gsp);
    dim3 g3((NB * HH * WW / 4) / 256);      // 1024 blocks
    combine_kernel<<<g3, blk, 0, stream>>>(gsp, out);
}